// Round 6
// baseline (1208.301 us; speedup 1.0000x reference)
//
#include <hip/hip_runtime.h>
#include <hip/hip_bf16.h>
#include <math.h>

typedef __attribute__((ext_vector_type(8))) short short8;
typedef __attribute__((ext_vector_type(4))) float f32x4;
typedef __attribute__((ext_vector_type(4))) unsigned u32x4;
typedef unsigned short u16;
typedef unsigned long long u64;

__device__ __forceinline__ u16 f2bf(float f) {
    union { float f; unsigned u; } v; v.f = f;
    unsigned r = v.u + 0x7fffu + ((v.u >> 16) & 1u);   // RNE
    return (u16)(r >> 16);
}
__device__ __forceinline__ float bf2f(u16 b) {
    union { unsigned u; float f; } v; v.u = ((unsigned)b) << 16;
    return v.f;
}
__device__ __forceinline__ float fast_sigmoid(float x) {
    return __builtin_amdgcn_rcpf(1.f + __expf(-x));
}
__device__ __forceinline__ float fast_tanh(float x) {
    return 1.f - 2.f * __builtin_amdgcn_rcpf(1.f + __expf(2.f * x));
}
// cached (L1/L2) pipelined 16-B load; asm so it can't be hoisted above gates.
__device__ __forceinline__ u32x4 ldg16(const void* p) {
    u32x4 r;
    asm volatile("global_load_dwordx4 %0, %1, off"
                 : "=v"(r) : "v"(p) : "memory");
    return r;
}
// early-issue coherent counter load (value checked much later, in-register)
__device__ __forceinline__ unsigned ldg_ctr(const unsigned* p) {
    unsigned r;
    asm volatile("global_load_dword %0, %1, off sc0 sc1"
                 : "=v"(r) : "v"(p) : "memory");
    return r;
}

// ---------------- consolidated prep kernel ----------------
__device__ __forceinline__ void tr_tile(const float* __restrict__ W,
                                        u16* __restrict__ WT, int K, int N,
                                        int bid, int tid, float (*tile)[33]) {
    int gx = N >> 5;
    int bx = bid % gx, by = bid / gx;
    int n0 = bx * 32, k0 = by * 32;
    int tx = tid & 31, ty = tid >> 5;
    #pragma unroll
    for (int j = 0; j < 32; j += 8)
        tile[ty + j][tx] = W[(size_t)(k0 + ty + j) * N + n0 + tx];
    __syncthreads();
    #pragma unroll
    for (int j = 0; j < 32; j += 8)
        WT[(size_t)(n0 + ty + j) * K + k0 + tx] = f2bf(tile[tx][ty + j]);
}

__global__ __launch_bounds__(256) void k_prep(
    const float* __restrict__ x, u16* __restrict__ Xb,
    const float* __restrict__ h0, u16* __restrict__ hs0, u16* __restrict__ hs1,
    unsigned* __restrict__ ctr,
    const float* __restrict__ Wpre, u16* __restrict__ WTpre,
    const float* __restrict__ Wi0, u16* __restrict__ WTi0,
    const float* __restrict__ Wh0, u16* __restrict__ WTh0,
    const float* __restrict__ Wi1, u16* __restrict__ WTi1,
    const float* __restrict__ Wh1, u16* __restrict__ WTh1,
    const float* __restrict__ Wpost, u16* __restrict__ WTpost,
    const float* __restrict__ Wout, u16* __restrict__ WTout) {
    __shared__ float tile[32][33];
    int bid = blockIdx.x, tid = threadIdx.x;
    if (bid == 0) {                                      // zero 64B-stride counters
        for (int i = tid; i < 4096; i += 256) ctr[i] = 0u;
        return;
    }
    bid -= 1;
    if (bid < 16384) {                                   // x -> bf16
        int i = bid * 256 + tid;
        Xb[i] = f2bf(x[i]);
        return;
    }
    bid -= 16384;
    if (bid < 512) {                                     // h0 -> hs slot-0 layout
        int i = bid * 256 + tid;                         // 131072 threads
        int layer = i >> 16, j = i & 65535;
        int b = j >> 10, jj = j & 1023;
        u16 v = f2bf(h0[(size_t)layer * 65536 + j]);
        u16* dst = layer ? hs1 : hs0;
        dst[(size_t)(jj >> 3) * 512 + b * 8 + (jj & 7)] = v;
        return;
    }
    bid -= 512;
    if (bid < 512)  { tr_tile(Wpre,  WTpre,  512,  1024, bid, tid, tile); return; }
    bid -= 512;
    if (bid < 4096) { tr_tile(Wi0,   WTi0,   1024, 4096, bid, tid, tile); return; }
    bid -= 4096;
    if (bid < 4096) { tr_tile(Wh0,   WTh0,   1024, 4096, bid, tid, tile); return; }
    bid -= 4096;
    if (bid < 4096) { tr_tile(Wi1,   WTi1,   1024, 4096, bid, tid, tile); return; }
    bid -= 4096;
    if (bid < 4096) { tr_tile(Wh1,   WTh1,   1024, 4096, bid, tid, tile); return; }
    bid -= 4096;
    if (bid < 1024) { tr_tile(Wpost, WTpost, 1024, 1024, bid, tid, tile); return; }
    bid -= 1024;
    tr_tile(Wout, WTout, 1024, 32, bid, tid, tile);      // 32 tiles
}
#define PREP_BLOCKS (1 + 16384 + 512 + 512 + 4 * 4096 + 1024 + 32)

// ---------------- generic bf16 MFMA GEMM ----------------
template <int MODE>
__global__ __launch_bounds__(256) void k_gemm(const u16* __restrict__ A,
                                              const u16* __restrict__ BT,
                                              const float* __restrict__ bias,
                                              void* __restrict__ Cout,
                                              int M, int N, int K) {
    const int w = threadIdx.x >> 6, l = threadIdx.x & 63;
    const int lm = l & 15, lq = l >> 4;
    const int r0 = blockIdx.y * 64 + w * 16;
    const int c0 = blockIdx.x * 64;
    const u16* arow = A + (size_t)(r0 + lm) * K + lq * 8;
    const u16* bp0 = BT + (size_t)(c0 + lm) * K + lq * 8;
    const u16* bp1 = bp0 + (size_t)16 * K;
    const u16* bp2 = bp0 + (size_t)32 * K;
    const u16* bp3 = bp0 + (size_t)48 * K;
    f32x4 acc0 = {0.f, 0.f, 0.f, 0.f}, acc1 = acc0, acc2 = acc0, acc3 = acc0;
    for (int k0 = 0; k0 < K; k0 += 32) {
        short8 a = *(const short8*)(arow + k0);
        acc0 = __builtin_amdgcn_mfma_f32_16x16x32_bf16(a, *(const short8*)(bp0 + k0), acc0, 0, 0, 0);
        acc1 = __builtin_amdgcn_mfma_f32_16x16x32_bf16(a, *(const short8*)(bp1 + k0), acc1, 0, 0, 0);
        acc2 = __builtin_amdgcn_mfma_f32_16x16x32_bf16(a, *(const short8*)(bp2 + k0), acc2, 0, 0, 0);
        acc3 = __builtin_amdgcn_mfma_f32_16x16x32_bf16(a, *(const short8*)(bp3 + k0), acc3, 0, 0, 0);
    }
    f32x4 accs[4] = {acc0, acc1, acc2, acc3};
    #pragma unroll
    for (int nt = 0; nt < 4; nt++) {
        #pragma unroll
        for (int r = 0; r < 4; r++) {
            int row = r0 + lq * 4 + r;          // C/D layout: row=(l>>4)*4+reg
            int col = c0 + nt * 16 + lm;        //             col=l&15
            float v = accs[nt][r] + bias[col];
            if (MODE == 0) {
                ((float*)Cout)[(size_t)row * N + col] = v;
            } else {
                if (MODE == 2) v = fmaxf(v, 0.f);
                ((u16*)Cout)[(size_t)row * N + col] = f2bf(v);
            }
        }
    }
}

// ---------------- LayerNorm + ReLU -> scan-layout preact ----------------
__global__ __launch_bounds__(256) void k_ln_relu(const float* __restrict__ X,
                                                 const float* __restrict__ scale,
                                                 const float* __restrict__ bias,
                                                 u16* __restrict__ preS) {
    const int N = 1024;
    int row = blockIdx.x;
    int b = row >> 7, t = row & 127;
    const float* x = X + (size_t)row * N;
    __shared__ float vbuf[1024];
    float s = 0.f, ss = 0.f;
    float vals[4];
    #pragma unroll
    for (int j = 0; j < 4; j++) {
        float v = x[threadIdx.x + 256 * j];
        vals[j] = v; s += v; ss += v * v;
    }
    #pragma unroll
    for (int o = 32; o > 0; o >>= 1) { s += __shfl_down(s, o); ss += __shfl_down(ss, o); }
    __shared__ float rs[4], rss[4];
    int w = threadIdx.x >> 6;
    if ((threadIdx.x & 63) == 0) { rs[w] = s; rss[w] = ss; }
    __syncthreads();
    __shared__ float smu, sinv;
    if (threadIdx.x == 0) {
        float a = rs[0] + rs[1] + rs[2] + rs[3];
        float bq = rss[0] + rss[1] + rss[2] + rss[3];
        float mu = a * (1.f / N);
        float var = bq * (1.f / N) - mu * mu;
        smu = mu; sinv = rsqrtf(var + 1e-6f);
    }
    __syncthreads();
    float mu = smu, inv = sinv;
    #pragma unroll
    for (int j = 0; j < 4; j++) {
        int i = threadIdx.x + 256 * j;
        float v = (vals[j] - mu) * inv * scale[i] + bias[i];
        vbuf[i] = fmaxf(v, 0.f);
    }
    __syncthreads();
    if (threadIdx.x < 128) {
        int g = threadIdx.x;
        union { u16 h[8]; u32x4 v; } pk;
        #pragma unroll
        for (int e = 0; e < 8; e++) pk.h[e] = f2bf(vbuf[g * 8 + e]);
        *(u32x4*)(preS + (size_t)t * 65536 + (size_t)g * 512 + b * 8) = pk.v;
    }
}

// ---------------- fused symmetric 2-layer persistent LSTM scan ----------------
// 256 blocks x 512 threads, 1 block/CU. Blocks 0..127 = layer 0, 128..255 =
// layer 1 (lagging one publish). z = [x_in ; h_prev] @ [Wi ; Wh] + b, K=2048;
// Wi|Wh slice (128 KB) LDS-resident in fragment order.
//
// ROUND-6: INTERLEAVED K-split. Waves are no longer dedicated to one data
// half (old kp=1 waves had zero ready work to hide the poll under). Group
// grp=w>>2 owns K = x[grp*512 .. +512) U h[grp*512 .. +512): per wave
// 16 READY chunks + 16 DYNAMIC chunks. Schedule per step per wave:
//   (role1 only) gate: own-role ctrs >= t  (near-always instant)
//   issue mid-check ctr loads (asm, 2/lane) -- RT hidden under:
//   16 ready chunks (role0: preS[t] true-static ; role1: hs1[t])
//   in-register check of pre-issued ctr values (spin only on miss)
//   16 dynamic chunks (role0: hs0[t] need role0>=t ; role1: hs0[t+1] >= t+1)
// Post-detect exposure halved; poll RT removed from the common-case chain.
// whs fragment layout unchanged (group base offsets select fi ranges).
// zbuf stride 33->34: gates-phase z[b*33+u] reads were 8-way bank conflicts
// (bank=(33b+u)%32=b+u); stride 34 -> (2b+u)%32, max 2-way = free.
// Sync/publish/tail: bit-identical to round-2 known-good (64B-stride ctrs,
// plain per-block publish store). Accs back to simple 2-chain (round-5
// showed 4-way split neutral).
#define FBLOCKS 256
__global__ __launch_bounds__(512, 1) void k_lstm_fused(
    const u16* __restrict__ WiT0, const u16* __restrict__ WhT0,
    const u16* __restrict__ WiT1, const u16* __restrict__ WhT1,
    const u16* __restrict__ preS, const float* __restrict__ b0v,
    const float* __restrict__ b1v, const float* __restrict__ c0_all,
    u16* __restrict__ hs0, u16* __restrict__ hs1, u16* __restrict__ Hp,
    float* __restrict__ out, unsigned* __restrict__ ctr) {
    const int bk = blockIdx.x;
    const int role = bk >> 7;          // 0: layer0, 1: layer1
    const int bkl = bk & 127;
    const int tid = threadIdx.x;
    const int w = tid >> 6, l = tid & 63, lm = l & 15, lq = l >> 4;
    const int grp = w >> 2, rt = w & 3;

    __shared__ u16 whs[65536];          // 128 KB fragment-ordered [Wi;Wh]
    __shared__ float zbuf[2 * 64 * 34]; // [grp][batch][32 cols], pad 34

    // ---- stage Wi|Wh slices in fragment order (dst = whs + f*8) — unchanged
    {
        const u16* Wx = role ? WiT1 : WiT0;
        const u16* Wh = role ? WhT1 : WhT0;
        for (int f = tid; f < 8192; f += 512) {
            int flm = f & 15, flq = (f >> 4) & 3;
            int fi = (f >> 6) & 31;
            int rest = f >> 11;
            int fg = rest & 1, fkp = (rest >> 1) & 1;
            int lc = fg * 16 + flm;
            int gcolw = (lc >> 3) * 1024 + bkl * 8 + (lc & 7);
            int k = fi * 32 + flq * 8;
            const u16* src = (fkp == 0 ? Wx : Wh) + (size_t)gcolw * 1024 + k;
            *(short8*)(whs + (size_t)f * 8) = *(const short8*)src;
        }
    }
    const int u = tid & 7, b = tid >> 3;
    const int gcol = bkl * 8 + u;
    float c = (c0_all + (size_t)role * 65536)[(size_t)b * 1024 + gcol];
    const float* bv = role ? b1v : b0v;
    float bi0 = bv[gcol], bi1 = bv[1024 + gcol];
    float bi2 = bv[2048 + gcol], bi3 = bv[3072 + gcol];
    u16* hs_my = role ? hs1 : hs0;
    float* c_out = out + (size_t)role * 65536;
    float* h_out = out + 131072 + (size_t)role * 65536;
    const int lanoff = (lq * 16 + lm) * 8;
    // B fragment bases: group grp covers fi in [grp*16, grp*16+16) of each half
    const u16* bx0 = whs + grp * 8192 + lanoff;          // x-half (Wi), cols 0-15
    const u16* bx1 = bx0 + 16384;                        // x-half, cols 16-31
    const u16* bh0 = whs + 32768 + grp * 8192 + lanoff;  // h-half (Wh), cols 0-15
    const u16* bh1 = bh0 + 16384;
    const u16* bS0 = role ? bh0 : bx0; const u16* bS1 = role ? bh1 : bx1;
    const u16* bD0 = role ? bx0 : bh0; const u16* bD1 = role ? bx1 : bh1;
    const int aoff = grp * 32768 + lq * 512 + (rt * 16 + lm) * 8;
    __syncthreads();

    for (int t = 0; t < 128; t++) {
        // ---- role-1 gate: own-role peers must have published step t
        // (hs1[t] loads below are plain; data must exist before issue)
        if (role && t > 0) {
            for (;;) {
                unsigned a0 = __hip_atomic_load(&ctr[(128 + l) * 16], __ATOMIC_RELAXED,
                                                __HIP_MEMORY_SCOPE_AGENT);
                unsigned a1 = __hip_atomic_load(&ctr[(192 + l) * 16], __ATOMIC_RELAXED,
                                                __HIP_MEMORY_SCOPE_AGENT);
                if (__all((a0 >= (unsigned)t) && (a1 >= (unsigned)t))) break;
                __builtin_amdgcn_s_sleep(1);
            }
        }
        // ---- early-issue mid-check counter loads (role-0 lines); RT hides
        // under the ready half-ladder below.
        unsigned e0 = ldg_ctr(ctr + (size_t)l * 16);
        unsigned e1 = ldg_ctr(ctr + (size_t)(64 + l) * 16);

        const u16* sb = role ? hs1 + (size_t)t * 65536 : preS + (size_t)t * 65536;
        const u16* db = role ? hs0 + (size_t)(t + 1) * 65536 : hs0 + (size_t)t * 65536;
        const u16* arS = sb + aoff;
        const u16* arD = db + aoff;

        f32x4 acc0 = {0.f, 0.f, 0.f, 0.f}, acc1 = acc0;
        #define STEPF(Ai, i, Bp0, Bp1)                                            \
        {   union { u32x4 q; short8 v; } _a; _a.q = (Ai);                         \
            short8 _b0 = *(const short8*)((Bp0) + (i) * 512);                     \
            short8 _b1 = *(const short8*)((Bp1) + (i) * 512);                     \
            acc0 = __builtin_amdgcn_mfma_f32_16x16x32_bf16(_a.v, _b0, acc0, 0, 0, 0); \
            acc1 = __builtin_amdgcn_mfma_f32_16x16x32_bf16(_a.v, _b1, acc1, 0, 0, 0); }

        // ---- ready half: 16 chunks, no dependency wait
        u32x4 S0 = ldg16(arS +     0), S1 = ldg16(arS +  2048);
        u32x4 S2 = ldg16(arS +  4096), S3 = ldg16(arS +  6144);
        u32x4 S4 = ldg16(arS +  8192), S5 = ldg16(arS + 10240);
        u32x4 S6 = ldg16(arS + 12288), S7 = ldg16(arS + 14336);
        u32x4 S8 = ldg16(arS + 16384), S9 = ldg16(arS + 18432);
        u32x4 S10 = ldg16(arS + 20480), S11 = ldg16(arS + 22528);
        u32x4 S12 = ldg16(arS + 24576), S13 = ldg16(arS + 26624);
        u32x4 S14 = ldg16(arS + 28672), S15 = ldg16(arS + 30720);
        // 18 outstanding (e0,e1,S0..S15); vmcnt(8) -> e0,e1,S0..S7 complete
        asm volatile("s_waitcnt vmcnt(8)"
                     : "+v"(e0), "+v"(e1),
                       "+v"(S0), "+v"(S1), "+v"(S2), "+v"(S3),
                       "+v"(S4), "+v"(S5), "+v"(S6), "+v"(S7) :: "memory");
        STEPF(S0, 0, bS0, bS1) STEPF(S1, 1, bS0, bS1)
        STEPF(S2, 2, bS0, bS1) STEPF(S3, 3, bS0, bS1)
        STEPF(S4, 4, bS0, bS1) STEPF(S5, 5, bS0, bS1)
        STEPF(S6, 6, bS0, bS1) STEPF(S7, 7, bS0, bS1)
        asm volatile("s_waitcnt vmcnt(0)"
                     : "+v"(S8), "+v"(S9), "+v"(S10), "+v"(S11),
                       "+v"(S12), "+v"(S13), "+v"(S14), "+v"(S15) :: "memory");
        STEPF(S8, 8, bS0, bS1) STEPF(S9, 9, bS0, bS1)
        STEPF(S10, 10, bS0, bS1) STEPF(S11, 11, bS0, bS1)
        STEPF(S12, 12, bS0, bS1) STEPF(S13, 13, bS0, bS1)
        STEPF(S14, 14, bS0, bS1) STEPF(S15, 15, bS0, bS1)

        // ---- mid-check: dynamic half's producers (role-0 lines)
        {
            unsigned need = (unsigned)(role ? t + 1 : t);
            if (need > 0 &&
                !__all((int)((e0 >= need) && (e1 >= need)))) {
                for (;;) {
                    unsigned a0 = __hip_atomic_load(&ctr[l * 16], __ATOMIC_RELAXED,
                                                    __HIP_MEMORY_SCOPE_AGENT);
                    unsigned a1 = __hip_atomic_load(&ctr[(64 + l) * 16], __ATOMIC_RELAXED,
                                                    __HIP_MEMORY_SCOPE_AGENT);
                    if (__all((a0 >= need) && (a1 >= need))) break;
                    __builtin_amdgcn_s_sleep(1);
                }
            }
        }

        // ---- dynamic half: 16 chunks
        u32x4 D0 = ldg16(arD +     0), D1 = ldg16(arD +  2048);
        u32x4 D2 = ldg16(arD +  4096), D3 = ldg16(arD +  6144);
        u32x4 D4 = ldg16(arD +  8192), D5 = ldg16(arD + 10240);
        u32x4 D6 = ldg16(arD + 12288), D7 = ldg16(arD + 14336);
        u32x4 D8 = ldg16(arD + 16384), D9 = ldg16(arD + 18432);
        u32x4 D10 = ldg16(arD + 20480), D11 = ldg16(arD + 22528);
        u32x4 D12 = ldg16(arD + 24576), D13 = ldg16(arD + 26624);
        u32x4 D14 = ldg16(arD + 28672), D15 = ldg16(arD + 30720);
        asm volatile("s_waitcnt vmcnt(8)"
                     : "+v"(D0), "+v"(D1), "+v"(D2), "+v"(D3),
                       "+v"(D4), "+v"(D5), "+v"(D6), "+v"(D7) :: "memory");
        STEPF(D0, 0, bD0, bD1) STEPF(D1, 1, bD0, bD1)
        STEPF(D2, 2, bD0, bD1) STEPF(D3, 3, bD0, bD1)
        STEPF(D4, 4, bD0, bD1) STEPF(D5, 5, bD0, bD1)
        STEPF(D6, 6, bD0, bD1) STEPF(D7, 7, bD0, bD1)
        asm volatile("s_waitcnt vmcnt(0)"
                     : "+v"(D8), "+v"(D9), "+v"(D10), "+v"(D11),
                       "+v"(D12), "+v"(D13), "+v"(D14), "+v"(D15) :: "memory");
        STEPF(D8, 8, bD0, bD1) STEPF(D9, 9, bD0, bD1)
        STEPF(D10, 10, bD0, bD1) STEPF(D11, 11, bD0, bD1)
        STEPF(D12, 12, bD0, bD1) STEPF(D13, 13, bD0, bD1)
        STEPF(D14, 14, bD0, bD1) STEPF(D15, 15, bD0, bD1)
        #undef STEPF

        // z partial -> LDS: row = rt*16 + lq*4 + r ; cols lm / 16+lm
        {
            float* zb = zbuf + (size_t)grp * 2176;
            #pragma unroll
            for (int r = 0; r < 4; r++) {
                int row = rt * 16 + lq * 4 + r;
                zb[row * 34 + lm] = acc0[r];
                zb[row * 34 + 16 + lm] = acc1[r];
            }
        }
        __syncthreads();   // (1) zbuf complete

        // gates: thread (b,u); local col lc = gate*8+u ; z = grpX + grpY
        {
            const float* z0 = zbuf + (size_t)b * 34;
            const float* z1 = z0 + 2176;
            float gi = z0[u]      + z1[u]      + bi0;
            float gf = z0[8 + u]  + z1[8 + u]  + bi1;
            float gg = z0[16 + u] + z1[16 + u] + bi2;
            float go = z0[24 + u] + z1[24 + u] + bi3;
            gi = fast_sigmoid(gi);
            gf = fast_sigmoid(gf);
            gg = fast_tanh(gg);
            go = fast_sigmoid(go);
            c = gf * c + gi * gg;
            float h = go * fast_tanh(c);
            // pack batch row's 8 bf16 into one dwordx4; lane u==0 stores
            unsigned hv = (unsigned)f2bf(h);
            int base = l & 56;
            unsigned p0 = __shfl(hv, base + 0, 64) | (__shfl(hv, base + 1, 64) << 16);
            unsigned p1 = __shfl(hv, base + 2, 64) | (__shfl(hv, base + 3, 64) << 16);
            unsigned p2 = __shfl(hv, base + 4, 64) | (__shfl(hv, base + 5, 64) << 16);
            unsigned p3 = __shfl(hv, base + 6, 64) | (__shfl(hv, base + 7, 64) << 16);
            if (u == 0) {
                u32x4 pv = {p0, p1, p2, p3};
                u16* dst = hs_my + (size_t)(t + 1) * 65536 + (size_t)bkl * 512 + b * 8;
                asm volatile("global_store_dwordx4 %0, %1, off sc0 sc1"
                             :: "v"(dst), "v"(pv) : "memory");
                if (role) {   // plain store for the post-GEMM (read after kernel end)
                    u16* d2 = Hp + (size_t)(t * 64 + b) * 1024 + bkl * 8;
                    *(u32x4*)d2 = pv;
                }
            }
            if (t == 127) {
                c_out[(size_t)b * 1024 + gcol] = c;
                h_out[(size_t)b * 1024 + gcol] = h;
            }
        }
        __syncthreads();   // (2) zbuf consumed + vmcnt(0) drain: h stores visible

        // ---- publish arrival (slot per block, 64 B apart) -- plain store
        if (tid == 0)
            __hip_atomic_store(&ctr[bk * 16], (unsigned)(t + 1), __ATOMIC_RELAXED,
                               __HIP_MEMORY_SCOPE_AGENT);
    }
}

// ---------------- logits: [8192,1024]bf16 @ WoT[32,1024]bf16 + b_out -> f32 ----------------
__global__ __launch_bounds__(256) void k_logits(const u16* __restrict__ Pact,
                                                const u16* __restrict__ WoT,
                                                const float* __restrict__ bout,
                                                float* __restrict__ out) {
    int r = blockIdx.x * 8 + (threadIdx.x >> 5);
    int n = threadIdx.x & 31;
    const u16* a = Pact + (size_t)r * 1024;
    const u16* wv = WoT + (size_t)n * 1024;
    float s = 0.f;
    for (int k = 0; k < 1024; k += 8) {
        short8 av = *(const short8*)(a + k);
        short8 wvv = *(const short8*)(wv + k);
        #pragma unroll
        for (int j = 0; j < 8; j++)
            s += bf2f((u16)av[j]) * bf2f((u16)wvv[j]);
    }
    int t = r >> 6, b = r & 63;
    out[((size_t)b * 128 + t) * 32 + n] = s + bout[n];
}

// ---------------- launcher ----------------
extern "C" void kernel_launch(void* const* d_in, const int* in_sizes, int n_in,
                              void* d_out, int out_size, void* d_ws, size_t ws_size,
                              hipStream_t stream) {
    const float* x      = (const float*)d_in[0];
    const float* c0     = (const float*)d_in[1];
    const float* h0     = (const float*)d_in[2];
    const float* W_pre  = (const float*)d_in[3];
    const float* b_pre  = (const float*)d_in[4];
    const float* ln_s   = (const float*)d_in[5];
    const float* ln_b   = (const float*)d_in[6];
    const float* Wi0    = (const float*)d_in[7];
    const float* Wh0    = (const float*)d_in[8];
    const float* b0     = (const float*)d_in[9];
    const float* Wi1    = (const float*)d_in[10];
    const float* Wh1    = (const float*)d_in[11];
    const float* b1     = (const float*)d_in[12];
    const float* W_post = (const float*)d_in[13];
    const float* b_post = (const float*)d_in[14];
    const float* W_out  = (const float*)d_in[15];
    const float* b_out  = (const float*)d_in[16];
    float* out = (float*)d_out;

    char* ws = (char*)d_ws;
    size_t off = 0;
    auto alloc = [&](size_t bytes) {
        void* p = ws + off;
        off += (bytes + 255) & ~(size_t)255;
        return p;
    };
    u16* WTpre  = (u16*)alloc((size_t)1024 * 512 * 2);
    u16* WTi0   = (u16*)alloc((size_t)4096 * 1024 * 2);
    u16* WTh0   = (u16*)alloc((size_t)4096 * 1024 * 2);
    u16* WTi1   = (u16*)alloc((size_t)4096 * 1024 * 2);
    u16* WTh1   = (u16*)alloc((size_t)4096 * 1024 * 2);
    u16* WTpost = (u16*)alloc((size_t)1024 * 1024 * 2);
    u16* WTout  = (u16*)alloc((size_t)32 * 1024 * 2);
    u16* Xb     = (u16*)alloc((size_t)8192 * 512 * 2);
    u16* preS   = (u16*)alloc((size_t)128 * 65536 * 2);   // preact, scan layout
    u16* hs0    = (u16*)alloc((size_t)129 * 65536 * 2);
    u16* hs1    = (u16*)alloc((size_t)129 * 65536 * 2);
    u16* postact= (u16*)alloc((size_t)8192 * 1024 * 2);
    unsigned* ctr = (unsigned*)alloc(32768);
    void* unionreg = alloc((size_t)8192 * 4096 * 2); // pre_f32 (32MB) / Hplain (16MB)
    float* pre_f32 = (float*)unionreg;
    u16* Hplain = (u16*)unionreg;

    // consolidated prep: ctr zero + x/h0 conversions + all weight transposes
    k_prep<<<PREP_BLOCKS, 256, 0, stream>>>(
        x, Xb, h0, hs0, hs1, ctr,
        W_pre, WTpre, Wi0, WTi0, Wh0, WTh0, Wi1, WTi1, Wh1, WTh1,
        W_post, WTpost, W_out, WTout);

    // pre: Dense + LN + relu (-> scan-layout preS)
    k_gemm<0><<<dim3(16, 128), 256, 0, stream>>>(Xb, WTpre, b_pre, pre_f32, 8192, 1024, 512);
    k_ln_relu<<<8192, 256, 0, stream>>>(pre_f32, ln_s, ln_b, preS);

    // fused symmetric 2-layer pipelined scan (Zi0 GEMM folded in)
    {
        const u16* WiT0_ = WTi0; const u16* WhT0_ = WTh0;
        const u16* WiT1_ = WTi1; const u16* WhT1_ = WTh1;
        const u16* preS_ = preS; const float* b0_ = b0; const float* b1_ = b1;
        const float* c0_ = c0; u16* hs0_ = hs0; u16* hs1_ = hs1;
        u16* Hp_ = Hplain; float* out_ = out; unsigned* ctr_ = ctr;
        void* args[] = {&WiT0_, &WhT0_, &WiT1_, &WhT1_, &preS_, &b0_, &b1_,
                        &c0_, &hs0_, &hs1_, &Hp_, &out_, &ctr_};
        hipLaunchCooperativeKernel((void*)k_lstm_fused, dim3(FBLOCKS), dim3(512),
                                   args, 0, stream);
    }

    // post Dense+relu, then logits
    k_gemm<2><<<dim3(16, 128), 256, 0, stream>>>(Hplain, WTpost, b_post, postact,
                                                 8192, 1024, 1024);
    k_logits<<<1024, 256, 0, stream>>>(postact, WTout, b_out, out + 262144);
}